// Round 9
// baseline (726.071 us; speedup 1.0000x reference)
//
#include <hip/hip_runtime.h>
#include <hip/hip_cooperative_groups.h>

// Capsule routing, B=64 R=2048 C=32 O=32 I=16, 3 routing iters.
// u_hat never materialized; recomputed per pass. Logit telescoping:
// b1 = u.v1 ; b2 = u.(v1+v2).
//
// R20 = R18 resubmit x2 (R18/R19 benches GPUAcquisitionTimeout; no data).
// R18: COOPERATIVE MEGA-KERNEL (diagnostic + structural fusion).
//   Post-mortem R15: NG4->2 paid -14us (= its HBM arithmetic, ~100MB).
//   Model says upass ~25us; measured ~70-75us each: 3x unexplained, and
//   ALL top-5 rocprof rows are the harness's 512MB poison fills (77us) so
//   upass counters are invisible. Fix the INFORMATION problem: fuse
//   3x upass + 3x reduce_squash into ONE cooperative kernel (256 blocks
//   = 1/CU, hipLaunchCooperativeKernel per guide sec 1) -> single ~230us
//   dispatch = top-1 row with MfmaUtil/VALUBusy/FETCH/Occupancy visible.
//   Bonus: x staged once (not 3x), 4-6 launch gaps removed, v1/v12 L2-hot.
//   Cost: 5 grid syncs. Bodies are identical R15 device functions.
// R15 (kept): NG=2 b-fusion, 32 b/block, W-fragment reuse for 2 b-tiles.
// R12 (kept): v in VGPRs; raw s_barrier + lgkmcnt-only drain in rr loop.
// R11 baseline: MFMA 16x16x16 per tile; D row=4q+reg, col=lane&15.

#define Bn 64
#define Rn 2048
#define Cn 32
#define On 32
#define In 16
#define RCH 16            // r per block
#define NRC2 (Rn / RCH)   // 128 r-chunks
#define NG 2              // fused b-groups of 32

namespace cg = cooperative_groups;

typedef _Float16 half4v __attribute__((ext_vector_type(4)));
typedef float floatx4 __attribute__((ext_vector_type(4)));

// W fp32 [2048,32,32,16] -> fp16 same layout. 8 elements/thread.
__global__ __launch_bounds__(256)
void wconv(const float* __restrict__ W, _Float16* __restrict__ Wh) {
    const size_t i = ((size_t)blockIdx.x * 256 + threadIdx.x) * 8;
    const float4 a = *(const float4*)(W + i);
    const float4 b = *(const float4*)(W + i + 4);
    union { _Float16 h[8]; uint4 u; } pk;
    pk.h[0] = (_Float16)a.x; pk.h[1] = (_Float16)a.y;
    pk.h[2] = (_Float16)a.z; pk.h[3] = (_Float16)a.w;
    pk.h[4] = (_Float16)b.x; pk.h[5] = (_Float16)b.y;
    pk.h[6] = (_Float16)b.z; pk.h[7] = (_Float16)b.w;
    *(uint4*)(Wh + i) = pk.u;
}

// One routing pass for this block's (rc, b0). s_part: [NRC2][64 b][1024 co] f32.
// Identical to R15's upass body (xs staging hoisted out to the mega kernel).
template <int PHASE>
__device__ __forceinline__ void upass_dev(
    const _Float16* __restrict__ Wh, const float* __restrict__ vroute,
    float* __restrict__ s_part, const _Float16* xs, float (&sums)[2][2][16][8],
    int w, int lane, int q, int bl, int rc, int b0) {

    // ---- v slice -> registers (r-invariant). g=0: b0+bl, g=1: b0+16+bl ----
    floatx4 v00[4], v01[4], v10[4], v11[4];
    if constexpr (PHASE > 0) {
        const float* vb0 = vroute + (size_t)(b0 + bl) * 1024 + 4 * q;
        const float* vb1 = vroute + (size_t)(b0 + 16 + bl) * 1024 + 4 * q;
#pragma unroll
        for (int t = 0; t < 4; ++t) {
            const int co = (w * 4 + t) * 32;
            v00[t] = *(const floatx4*)(vb0 + co);
            v01[t] = *(const floatx4*)(vb0 + co + 16);
            v10[t] = *(const floatx4*)(vb1 + co);
            v11[t] = *(const floatx4*)(vb1 + co + 16);
        }
    }

    floatx4 accS0[8], accS1[8];
#pragma unroll
    for (int m = 0; m < 8; ++m) {
        accS0[m] = (floatx4){0.f, 0.f, 0.f, 0.f};
        accS1[m] = (floatx4){0.f, 0.f, 0.f, 0.f};
    }

    // A base: W[r, co = w*128 + m*16 + bl, i = 4q..4q+3]; per-r stride 16384 halfs
    const _Float16* Wp = Wh + ((size_t)(rc * RCH) * 1024 + w * 128 + bl) * 16 + 4 * q;

    // prime fragments for rr=0
    half4v a[8];
#pragma unroll
    for (int m = 0; m < 8; ++m) a[m] = *(const half4v*)(Wp + m * 256);
    half4v bf0 = *(const half4v*)(xs + bl * 20 + 4 * q);
    half4v bf1 = *(const half4v*)(xs + (16 + bl) * 20 + 4 * q);

    for (int rr = 0; rr < RCH; ++rr) {
        const int rn = (rr + 1 < RCH) ? rr + 1 : rr;     // clamped prefetch idx
        const _Float16* Wn = Wp + (size_t)rn * 16384;

        if constexpr (PHASE == 0) {
#pragma unroll
            for (int m = 0; m < 8; ++m) {
                accS0[m] = __builtin_amdgcn_mfma_f32_16x16x16f16(a[m], bf0, accS0[m], 0, 0, 0);
                accS1[m] = __builtin_amdgcn_mfma_f32_16x16x16f16(a[m], bf1, accS1[m], 0, 0, 0);
            }
            const half4v bn0 = *(const half4v*)(xs + (rn * 32 + bl) * 20 + 4 * q);
            const half4v bn1 = *(const half4v*)(xs + (rn * 32 + 16 + bl) * 20 + 4 * q);
#pragma unroll
            for (int m = 0; m < 8; ++m) a[m] = *(const half4v*)(Wn + m * 256);
            bf0 = bn0; bf1 = bn1;
        } else {
            floatx4 D0[8], D1[8];
#pragma unroll
            for (int m = 0; m < 8; ++m) {
                D0[m] = __builtin_amdgcn_mfma_f32_16x16x16f16(
                            a[m], bf0, (floatx4){0.f, 0.f, 0.f, 0.f}, 0, 0, 0);
                D1[m] = __builtin_amdgcn_mfma_f32_16x16x16f16(
                            a[m], bf1, (floatx4){0.f, 0.f, 0.f, 0.f}, 0, 0, 0);
            }

            // issue rr+1 fragment loads NOW; in flight across the barrier.
            const half4v bn0 = *(const half4v*)(xs + (rn * 32 + bl) * 20 + 4 * q);
            const half4v bn1 = *(const half4v*)(xs + (rn * 32 + 16 + bl) * 20 + 4 * q);
#pragma unroll
            for (int m = 0; m < 8; ++m) a[m] = *(const half4v*)(Wn + m * 256);
            bf0 = bn0; bf1 = bn1;

            // logits l[b,c] = sum_o u*v ; tile 2t: o=4q+reg, 2t+1: o=16+4q+reg
            float e0[4], e1[4], se0 = 0.f, se1 = 0.f;
#pragma unroll
            for (int t = 0; t < 4; ++t) {
                float lp0 = D0[2*t].x * v00[t].x + D0[2*t].y * v00[t].y +
                            D0[2*t].z * v00[t].z + D0[2*t].w * v00[t].w +
                            D0[2*t+1].x * v01[t].x + D0[2*t+1].y * v01[t].y +
                            D0[2*t+1].z * v01[t].z + D0[2*t+1].w * v01[t].w;
                float lp1 = D1[2*t].x * v10[t].x + D1[2*t].y * v10[t].y +
                            D1[2*t].z * v10[t].z + D1[2*t].w * v10[t].w +
                            D1[2*t+1].x * v11[t].x + D1[2*t+1].y * v11[t].y +
                            D1[2*t+1].z * v11[t].z + D1[2*t+1].w * v11[t].w;
                lp0 += __shfl_xor(lp0, 16, 64);   // sum over quads (o coverage)
                lp0 += __shfl_xor(lp0, 32, 64);
                lp1 += __shfl_xor(lp1, 16, 64);
                lp1 += __shfl_xor(lp1, 32, 64);
                e0[t] = __expf(lp0); se0 += e0[t]; // no max-subtract (|l| small)
                e1[t] = __expf(lp1); se1 += e1[t];
            }
            if (lane < 32) sums[rr & 1][q][bl][w] = (q == 0) ? se0 : se1;
            // lgkmcnt-only drain: LDS write visible, W loads stay in flight.
            asm volatile("s_waitcnt lgkmcnt(0)" ::: "memory");
            __builtin_amdgcn_s_barrier();
            asm volatile("" ::: "memory");
            const floatx4 sa0 = *(const floatx4*)(&sums[rr & 1][0][bl][0]);
            const floatx4 sa1 = *(const floatx4*)(&sums[rr & 1][0][bl][4]);
            const floatx4 sb0 = *(const floatx4*)(&sums[rr & 1][1][bl][0]);
            const floatx4 sb1 = *(const floatx4*)(&sums[rr & 1][1][bl][4]);
            const float tot0 = sa0.x + sa0.y + sa0.z + sa0.w +
                               sa1.x + sa1.y + sa1.z + sa1.w;
            const float tot1 = sb0.x + sb0.y + sb0.z + sb0.w +
                               sb1.x + sb1.y + sb1.z + sb1.w;
            const float winv0 = __builtin_amdgcn_rcpf(tot0);
            const float winv1 = __builtin_amdgcn_rcpf(tot1);
#pragma unroll
            for (int t = 0; t < 4; ++t) {
                const float wt0 = e0[t] * winv0;
                const float wt1 = e1[t] * winv1;
                accS0[2*t]   += wt0 * D0[2*t];
                accS0[2*t+1] += wt0 * D0[2*t+1];
                accS1[2*t]   += wt1 * D1[2*t];
                accS1[2*t+1] += wt1 * D1[2*t+1];
            }
        }
    }

    // store: co = w*128 + m*16 + 4q + reg; g=0 rows b0+bl, g=1 rows b0+16+bl
    const size_t sb = (((size_t)rc * 64 + b0 + bl)) * 1024 + w * 128 + 4 * q;
#pragma unroll
    for (int m = 0; m < 8; ++m) {
        *(floatx4*)(s_part + sb + m * 16) = accS0[m];
        *(floatx4*)(s_part + sb + (size_t)16 * 1024 + m * 16) = accS1[m];
    }
}

// Fused reduce(128 rc-partials) + squash, as a device fn on 256 blocks x 512 thr.
// Virtual-block remap of the old 512-block x 256-thr grid:
//   vb = blockIdx*2 + (tid>>8) in [0,512) ; b = vb>>3 ; oct = vb&7 ; t = tid&255.
// Old intra-wave shfl layout preserved: o = t&31 = lane&31.
__device__ __forceinline__ void rs_dev(
    const float* __restrict__ sp, float scale,
    float* __restrict__ vout, const float* __restrict__ vprev,
    float* __restrict__ vsum, float (&red)[2][8][128], int tid, int bx) {
    const int vb = bx * 2 + (tid >> 8);
    const int half = tid >> 8;
    const int b = vb >> 3, oct = vb & 7;
    const int t = tid & 255;
    const int kg = t >> 5, ci = t & 31;
    const size_t base = (size_t)b * 1024 + (size_t)oct * 128 + (size_t)ci * 4;

    floatx4 acc0 = (floatx4){0.f, 0.f, 0.f, 0.f};
    floatx4 acc1 = (floatx4){0.f, 0.f, 0.f, 0.f};
#pragma unroll
    for (int k = kg * 16; k < kg * 16 + 16; k += 2) {
        acc0 += *(const floatx4*)(sp + (size_t)k * 65536 + base);
        acc1 += *(const floatx4*)(sp + (size_t)(k + 1) * 65536 + base);
    }
    const floatx4 acc = acc0 + acc1;

    *(floatx4*)(&red[half][kg][ci * 4]) = acc;
    __syncthreads();

    if (t < 128) {                     // element f = t : c = oct*4 + (t>>5), o = t&31
        float s = 0.f;
#pragma unroll
        for (int g = 0; g < 8; ++g) s += red[half][g][t];
        s *= scale;
        float n2 = s * s;              // norm over o: lane bits 0..4
        n2 += __shfl_xor(n2, 1, 64);
        n2 += __shfl_xor(n2, 2, 64);
        n2 += __shfl_xor(n2, 4, 64);
        n2 += __shfl_xor(n2, 8, 64);
        n2 += __shfl_xor(n2, 16, 64);
        const float norm = sqrtf(n2);
        const float f = (n2 / (1.f + n2)) / (norm + 1e-8f);
        const float vv = s * f;
        const size_t o = (size_t)b * 1024 + (size_t)oct * 128 + t;
        if (vout) vout[o] = vv;
        if (vsum) vsum[o] = vv + vprev[o];
    }
}

// The whole 3-iteration routing in one cooperative kernel. 256 blocks x 512 thr
// = 1 block/CU (co-resident). 5 grid syncs.
__global__ __launch_bounds__(512, 2)
void mega(const float* __restrict__ x, const _Float16* __restrict__ Wh,
          float* __restrict__ s_part, float* __restrict__ v1,
          float* __restrict__ v12, float* __restrict__ out) {
    const int tid  = threadIdx.x;
    const int w    = tid >> 6;      // wave 0..7 -> c = 4w..4w+3
    const int lane = tid & 63;
    const int q    = lane >> 4;     // quad
    const int bl   = lane & 15;     // A row / B col / D col

    // XCD swizzle: the 2 bg-blocks of one rc are L and L+8 -> same XCD.
    const int L  = blockIdx.x;                  // [0,256)
    const int bg = (L >> 3) & 1;
    const int rc = (L & 7) | ((L >> 4) << 3);   // [0,128)
    const int b0 = bg * 32;

    __shared__ __attribute__((aligned(16))) _Float16 xs[RCH * 32 * 20];
    __shared__ __attribute__((aligned(16))) float sums[2][2][16][8];
    __shared__ __attribute__((aligned(16))) float red[2][8][128];

    // ---- preload x chunk ONCE (shared by all 3 passes): 16 r x 32 b x 16 i ----
#pragma unroll
    for (int k = 0; k < 4; ++k) {
        const int u  = tid + k * 512;           // [0,2048)
        const int rr = u >> 7, bb = (u >> 2) & 31, iq = u & 3;
        const float4 xv = *(const float4*)(x + (size_t)(b0 + bb) * (Rn * In) +
                                           (size_t)(rc * RCH + rr) * In + iq * 4);
        union { _Float16 h[4]; uint2 u2; } p;
        p.h[0] = (_Float16)xv.x; p.h[1] = (_Float16)xv.y;
        p.h[2] = (_Float16)xv.z; p.h[3] = (_Float16)xv.w;
        *(uint2*)(xs + (rr * 32 + bb) * 20 + iq * 4) = p.u2;
    }
    __syncthreads();

    cg::grid_group gg = cg::this_grid();

    // iter 1: uniform coefficients; 1/32 applied as squash pre-scale
    upass_dev<0>(Wh, nullptr, s_part, xs, sums, w, lane, q, bl, rc, b0);
    __threadfence(); gg.sync();
    rs_dev(s_part, 1.f / 32.f, v1, nullptr, nullptr, red, tid, L);
    __threadfence(); gg.sync();

    // iter 2: logits = u.v1 ; keep only v12 = v1 + v2
    upass_dev<1>(Wh, v1, s_part, xs, sums, w, lane, q, bl, rc, b0);
    __threadfence(); gg.sync();
    rs_dev(s_part, 1.f, nullptr, v1, v12, red, tid, L);
    __threadfence(); gg.sync();

    // iter 3: logits = u.(v1+v2) ; output v3
    upass_dev<2>(Wh, v12, s_part, xs, sums, w, lane, q, bl, rc, b0);
    __threadfence(); gg.sync();
    rs_dev(s_part, 1.f, out, nullptr, nullptr, red, tid, L);
}

extern "C" void kernel_launch(void* const* d_in, const int* in_sizes, int n_in,
                              void* d_out, int out_size, void* d_ws, size_t ws_size,
                              hipStream_t stream) {
    const float* x = (const float*)d_in[0];   // [64,2048,16]
    const float* W = (const float*)d_in[1];   // [2048,32,32,16]
    float* out = (float*)d_out;               // [64,32,32]

    char* ws = (char*)d_ws;
    _Float16* Wh  = (_Float16*)ws;                              // 64 MB
    float* s_part = (float*)(ws + (size_t)67108864);            // 32 MB
    float* v1     = (float*)(ws + (size_t)67108864 + 33554432);             // 256 KB
    float* v12    = (float*)(ws + (size_t)67108864 + 33554432 + 262144);    // 256 KB

    wconv<<<16384, 256, 0, stream>>>(W, Wh);

    void* args[6] = {(void*)&x, (void*)&Wh, (void*)&s_part,
                     (void*)&v1, (void*)&v12, (void*)&out};
    hipLaunchCooperativeKernel((const void*)mega, dim3(NG * NRC2), dim3(512),
                               args, 0, stream);
}

// Round 13
// 298.228 us; speedup vs baseline: 2.4346x; 2.4346x over previous
//
#include <hip/hip_runtime.h>

// Capsule routing, B=64 R=2048 C=32 O=32 I=16, 3 routing iters.
// u_hat never materialized; recomputed per pass. Logit telescoping:
// b1 = u.v1 ; b2 = u.(v1+v2).
//
// R24 = R21 resubmit x3 (R21/R22/R23 benches GPUAcquisitionTimeout).
// R21: SPILL FIX. R18 mega (726us, reverted) exposed the hidden bottleneck:
//   VGPR_Count=128 with ~236 demand => ~100 spilled VGPRs in the rr loop,
//   MfmaUtil 1.9% / VALUBusy 4.4% / HBM 7.5% = pure latency starvation.
//   Measured launch_bounds semantics (512-thr blocks): bound=4 -> 64-VGPR
//   clamp (R6), bound=2 -> 128 (R18 counters). I.e. 2nd arg ~ blocks/CU;
//   waves/SIMD = 2*bound. Fix: bound=1 -> 2 waves/SIMD -> 256-VGPR cap,
//   fits the ~236 demand. Grid is 256 = 1 block/CU either way, so NO
//   occupancy loss. This retroactively explains why every scheduling fix
//   (R9/R10/R12) was neutral: the loop was spill-bound all along.
// R15 (kept, 297.5us baseline): NG=2 b-fusion, 32 b/block, W-fragment
//   reuse for 2 b-tiles; fused reduce_squash (512 blk).
// R12 (kept): v in VGPRs; raw s_barrier + lgkmcnt-only drain.
// R11 baseline: MFMA 16x16x16 per tile; D row=4q+reg, col=lane&15.

#define Bn 64
#define Rn 2048
#define Cn 32
#define On 32
#define In 16
#define RCH 16            // r per block
#define NRC2 (Rn / RCH)   // 128 r-chunks
#define NG 2              // fused b-groups of 32

typedef _Float16 half4v __attribute__((ext_vector_type(4)));
typedef float floatx4 __attribute__((ext_vector_type(4)));

// W fp32 [2048,32,32,16] -> fp16 same layout. 8 elements/thread.
__global__ __launch_bounds__(256)
void wconv(const float* __restrict__ W, _Float16* __restrict__ Wh) {
    const size_t i = ((size_t)blockIdx.x * 256 + threadIdx.x) * 8;
    const float4 a = *(const float4*)(W + i);
    const float4 b = *(const float4*)(W + i + 4);
    union { _Float16 h[8]; uint4 u; } pk;
    pk.h[0] = (_Float16)a.x; pk.h[1] = (_Float16)a.y;
    pk.h[2] = (_Float16)a.z; pk.h[3] = (_Float16)a.w;
    pk.h[4] = (_Float16)b.x; pk.h[5] = (_Float16)b.y;
    pk.h[6] = (_Float16)b.z; pk.h[7] = (_Float16)b.w;
    *(uint4*)(Wh + i) = pk.u;
}

// s_part: [NRC2][64 b][1024 co] f32 (32 MB)
template <int PHASE>
__global__ __launch_bounds__(512, 1)   // <-- R21: 256-VGPR cap, no spills
void upass(const float* __restrict__ x, const _Float16* __restrict__ Wh,
           const float* __restrict__ vroute, float* __restrict__ s_part) {
    const int tid  = threadIdx.x;
    const int w    = tid >> 6;      // wave 0..7 -> c = 4w..4w+3
    const int lane = tid & 63;
    const int q    = lane >> 4;     // quad
    const int bl   = lane & 15;     // A row / B col / D col

    // XCD swizzle: the 2 bg-blocks of one rc are L and L+8 -> same XCD, co-dispatched.
    const int L  = blockIdx.x;                  // [0,256)
    const int bg = (L >> 3) & 1;
    const int rc = (L & 7) | ((L >> 4) << 3);   // [0,128)
    const int b0 = bg * 32;

    // xs[rr][bb 32][20] halfs (pad 16->20: 8B-aligned b64, conflict-free)
    __shared__ __attribute__((aligned(16))) _Float16 xs[RCH * 32 * 20];
    __shared__ __attribute__((aligned(16))) float sums[2][2][16][8];

    // ---- v slice -> registers (r-invariant). g=0: b0+bl, g=1: b0+16+bl ----
    floatx4 v00[4], v01[4], v10[4], v11[4];
    if constexpr (PHASE > 0) {
        const float* vb0 = vroute + (size_t)(b0 + bl) * 1024 + 4 * q;
        const float* vb1 = vroute + (size_t)(b0 + 16 + bl) * 1024 + 4 * q;
#pragma unroll
        for (int t = 0; t < 4; ++t) {
            const int co = (w * 4 + t) * 32;
            v00[t] = *(const floatx4*)(vb0 + co);
            v01[t] = *(const floatx4*)(vb0 + co + 16);
            v10[t] = *(const floatx4*)(vb1 + co);
            v11[t] = *(const floatx4*)(vb1 + co + 16);
        }
    }

    // ---- preload x chunk -> fp16 LDS: 16 r x 32 b x 16 i ----
#pragma unroll
    for (int k = 0; k < 4; ++k) {
        const int u  = tid + k * 512;           // [0,2048)
        const int rr = u >> 7, bb = (u >> 2) & 31, iq = u & 3;
        const float4 xv = *(const float4*)(x + (size_t)(b0 + bb) * (Rn * In) +
                                           (size_t)(rc * RCH + rr) * In + iq * 4);
        union { _Float16 h[4]; uint2 u2; } p;
        p.h[0] = (_Float16)xv.x; p.h[1] = (_Float16)xv.y;
        p.h[2] = (_Float16)xv.z; p.h[3] = (_Float16)xv.w;
        *(uint2*)(xs + (rr * 32 + bb) * 20 + iq * 4) = p.u2;
    }
    __syncthreads();

    floatx4 accS0[8], accS1[8];
#pragma unroll
    for (int m = 0; m < 8; ++m) {
        accS0[m] = (floatx4){0.f, 0.f, 0.f, 0.f};
        accS1[m] = (floatx4){0.f, 0.f, 0.f, 0.f};
    }

    // A base: W[r, co = w*128 + m*16 + bl, i = 4q..4q+3]; per-r stride 16384 halfs
    const _Float16* Wp = Wh + ((size_t)(rc * RCH) * 1024 + w * 128 + bl) * 16 + 4 * q;

    // prime fragments for rr=0
    half4v a[8];
#pragma unroll
    for (int m = 0; m < 8; ++m) a[m] = *(const half4v*)(Wp + m * 256);
    half4v bf0 = *(const half4v*)(xs + bl * 20 + 4 * q);
    half4v bf1 = *(const half4v*)(xs + (16 + bl) * 20 + 4 * q);

    for (int rr = 0; rr < RCH; ++rr) {
        const int rn = (rr + 1 < RCH) ? rr + 1 : rr;     // clamped prefetch idx
        const _Float16* Wn = Wp + (size_t)rn * 16384;

        if constexpr (PHASE == 0) {
#pragma unroll
            for (int m = 0; m < 8; ++m) {
                accS0[m] = __builtin_amdgcn_mfma_f32_16x16x16f16(a[m], bf0, accS0[m], 0, 0, 0);
                accS1[m] = __builtin_amdgcn_mfma_f32_16x16x16f16(a[m], bf1, accS1[m], 0, 0, 0);
            }
            const half4v bn0 = *(const half4v*)(xs + (rn * 32 + bl) * 20 + 4 * q);
            const half4v bn1 = *(const half4v*)(xs + (rn * 32 + 16 + bl) * 20 + 4 * q);
#pragma unroll
            for (int m = 0; m < 8; ++m) a[m] = *(const half4v*)(Wn + m * 256);
            bf0 = bn0; bf1 = bn1;
        } else {
            floatx4 D0[8], D1[8];
#pragma unroll
            for (int m = 0; m < 8; ++m) {
                D0[m] = __builtin_amdgcn_mfma_f32_16x16x16f16(
                            a[m], bf0, (floatx4){0.f, 0.f, 0.f, 0.f}, 0, 0, 0);
                D1[m] = __builtin_amdgcn_mfma_f32_16x16x16f16(
                            a[m], bf1, (floatx4){0.f, 0.f, 0.f, 0.f}, 0, 0, 0);
            }

            // issue rr+1 fragment loads NOW; in flight across the barrier.
            const half4v bn0 = *(const half4v*)(xs + (rn * 32 + bl) * 20 + 4 * q);
            const half4v bn1 = *(const half4v*)(xs + (rn * 32 + 16 + bl) * 20 + 4 * q);
#pragma unroll
            for (int m = 0; m < 8; ++m) a[m] = *(const half4v*)(Wn + m * 256);
            bf0 = bn0; bf1 = bn1;

            // logits l[b,c] = sum_o u*v ; tile 2t: o=4q+reg, 2t+1: o=16+4q+reg
            float e0[4], e1[4], se0 = 0.f, se1 = 0.f;
#pragma unroll
            for (int t = 0; t < 4; ++t) {
                float lp0 = D0[2*t].x * v00[t].x + D0[2*t].y * v00[t].y +
                            D0[2*t].z * v00[t].z + D0[2*t].w * v00[t].w +
                            D0[2*t+1].x * v01[t].x + D0[2*t+1].y * v01[t].y +
                            D0[2*t+1].z * v01[t].z + D0[2*t+1].w * v01[t].w;
                float lp1 = D1[2*t].x * v10[t].x + D1[2*t].y * v10[t].y +
                            D1[2*t].z * v10[t].z + D1[2*t].w * v10[t].w +
                            D1[2*t+1].x * v11[t].x + D1[2*t+1].y * v11[t].y +
                            D1[2*t+1].z * v11[t].z + D1[2*t+1].w * v11[t].w;
                lp0 += __shfl_xor(lp0, 16, 64);   // sum over quads (o coverage)
                lp0 += __shfl_xor(lp0, 32, 64);
                lp1 += __shfl_xor(lp1, 16, 64);
                lp1 += __shfl_xor(lp1, 32, 64);
                e0[t] = __expf(lp0); se0 += e0[t]; // no max-subtract (|l| small)
                e1[t] = __expf(lp1); se1 += e1[t];
            }
            if (lane < 32) sums[rr & 1][q][bl][w] = (q == 0) ? se0 : se1;
            // lgkmcnt-only drain: LDS write visible, W loads stay in flight.
            asm volatile("s_waitcnt lgkmcnt(0)" ::: "memory");
            __builtin_amdgcn_s_barrier();
            asm volatile("" ::: "memory");
            const floatx4 sa0 = *(const floatx4*)(&sums[rr & 1][0][bl][0]);
            const floatx4 sa1 = *(const floatx4*)(&sums[rr & 1][0][bl][4]);
            const floatx4 sb0 = *(const floatx4*)(&sums[rr & 1][1][bl][0]);
            const floatx4 sb1 = *(const floatx4*)(&sums[rr & 1][1][bl][4]);
            const float tot0 = sa0.x + sa0.y + sa0.z + sa0.w +
                               sa1.x + sa1.y + sa1.z + sa1.w;
            const float tot1 = sb0.x + sb0.y + sb0.z + sb0.w +
                               sb1.x + sb1.y + sb1.z + sb1.w;
            const float winv0 = __builtin_amdgcn_rcpf(tot0);
            const float winv1 = __builtin_amdgcn_rcpf(tot1);
#pragma unroll
            for (int t = 0; t < 4; ++t) {
                const float wt0 = e0[t] * winv0;
                const float wt1 = e1[t] * winv1;
                accS0[2*t]   += wt0 * D0[2*t];
                accS0[2*t+1] += wt0 * D0[2*t+1];
                accS1[2*t]   += wt1 * D1[2*t];
                accS1[2*t+1] += wt1 * D1[2*t+1];
            }
        }
    }

    // store: co = w*128 + m*16 + 4q + reg; g=0 rows b0+bl, g=1 rows b0+16+bl
    const size_t sb = (((size_t)rc * 64 + b0 + bl)) * 1024 + w * 128 + 4 * q;
#pragma unroll
    for (int m = 0; m < 8; ++m) {
        *(floatx4*)(s_part + sb + m * 16) = accS0[m];
        *(floatx4*)(s_part + sb + (size_t)16 * 1024 + m * 16) = accS1[m];
    }
}

// Fused reduce(128 rc-partials) + squash. Grid: 64 b x 8 co-octs = 512 blocks.
// Each block: 256 thr = 8 k-groups x 32 float4 covering a 128-co slice
// (= 4 full capsules c, so the o-norm is block-local).
__global__ __launch_bounds__(256)
void reduce_squash(const float* __restrict__ sp, float scale,
                   float* __restrict__ vout, const float* __restrict__ vprev,
                   float* __restrict__ vsum) {
    const int b = blockIdx.x >> 3, oct = blockIdx.x & 7;
    const int t = threadIdx.x;
    const int kg = t >> 5, ci = t & 31;
    const size_t base = (size_t)b * 1024 + (size_t)oct * 128 + (size_t)ci * 4;

    floatx4 acc0 = (floatx4){0.f, 0.f, 0.f, 0.f};
    floatx4 acc1 = (floatx4){0.f, 0.f, 0.f, 0.f};
#pragma unroll
    for (int k = kg * 16; k < kg * 16 + 16; k += 2) {
        acc0 += *(const floatx4*)(sp + (size_t)k * 65536 + base);
        acc1 += *(const floatx4*)(sp + (size_t)(k + 1) * 65536 + base);
    }
    const floatx4 acc = acc0 + acc1;

    __shared__ __attribute__((aligned(16))) float red[8][128];
    *(floatx4*)(&red[kg][ci * 4]) = acc;
    __syncthreads();

    if (t < 128) {                     // element f = t : c = oct*4 + (t>>5), o = t&31
        float s = 0.f;
#pragma unroll
        for (int g = 0; g < 8; ++g) s += red[g][t];
        s *= scale;
        float n2 = s * s;              // norm over o: lane bits 0..4
        n2 += __shfl_xor(n2, 1, 64);
        n2 += __shfl_xor(n2, 2, 64);
        n2 += __shfl_xor(n2, 4, 64);
        n2 += __shfl_xor(n2, 8, 64);
        n2 += __shfl_xor(n2, 16, 64);
        const float norm = sqrtf(n2);
        const float f = (n2 / (1.f + n2)) / (norm + 1e-8f);
        const float vv = s * f;
        const size_t o = (size_t)b * 1024 + (size_t)oct * 128 + t;
        if (vout) vout[o] = vv;
        if (vsum) vsum[o] = vv + vprev[o];
    }
}

extern "C" void kernel_launch(void* const* d_in, const int* in_sizes, int n_in,
                              void* d_out, int out_size, void* d_ws, size_t ws_size,
                              hipStream_t stream) {
    const float* x = (const float*)d_in[0];   // [64,2048,16]
    const float* W = (const float*)d_in[1];   // [2048,32,32,16]
    float* out = (float*)d_out;               // [64,32,32]

    char* ws = (char*)d_ws;
    _Float16* Wh  = (_Float16*)ws;                              // 64 MB
    float* s_part = (float*)(ws + (size_t)67108864);            // 32 MB
    float* v1     = (float*)(ws + (size_t)67108864 + 33554432);             // 256 KB
    float* v12    = (float*)(ws + (size_t)67108864 + 33554432 + 262144);    // 256 KB

    const int ublocks = NG * NRC2;   // 256

    wconv<<<16384, 256, 0, stream>>>(W, Wh);

    // iter 1: uniform coefficients; 1/32 applied as squash pre-scale
    upass<0><<<ublocks, 512, 0, stream>>>(x, Wh, nullptr, s_part);
    reduce_squash<<<512, 256, 0, stream>>>(s_part, 1.f / 32.f, v1, nullptr, nullptr);

    // iter 2: logits = u.v1 ; keep only v12 = v1 + v2
    upass<1><<<ublocks, 512, 0, stream>>>(x, Wh, v1, s_part);
    reduce_squash<<<512, 256, 0, stream>>>(s_part, 1.f, nullptr, v1, v12);

    // iter 3: logits = u.(v1+v2) ; output v3
    upass<2><<<ublocks, 512, 0, stream>>>(x, Wh, v12, s_part);
    reduce_squash<<<512, 256, 0, stream>>>(s_part, 1.f, out, nullptr, nullptr);
}

// Round 16
// 292.938 us; speedup vs baseline: 2.4786x; 1.0181x over previous
//
#include <hip/hip_runtime.h>

// Capsule routing, B=64 R=2048 C=32 O=32 I=16, 3 routing iters.
// u_hat never materialized; recomputed per pass. Logit telescoping:
// b1 = u.v1 ; b2 = u.(v1+v2).
//
// R27 = R25 resubmit x2 (R25/R26 benches GPUAcquisitionTimeout; no data).
// R25: FOLD wconv INTO upass<0> (optimization + rocprof visibility).
//   Post-mortem R21: bound 2->1 (256-VGPR cap) NEUTRAL at 298us => the
//   7-launch upass was NOT spill-bound (mega's spills were mega-specific:
//   fences pinned live ranges). ~72us/upass still unexplained vs ~30us
//   model; upass has NEVER been visible in rocprof (harness 512MB fills
//   own all top-5 slots at 76-78us; upass ~72us sits just below).
//   Change: phase 0 reads W fp32 directly (float4/lane, coalesced 1KB
//   segments), converts in-reg for its MFMAs, bg==0 blocks persist fp16
//   to Wh for passes 1/2. Deletes the 30us wconv dispatch; upass<0>
//   grows to ~85-95us -> TOP-1 rocprof row with real counters.
// R21 (kept): __launch_bounds__(512,1) (256-VGPR cap; grid=256=1blk/CU).
// R15 (kept): NG=2 b-fusion, 32 b/block, W-fragment reuse for 2 b-tiles;
//   fused reduce_squash (512 blk).
// R12 (kept): v in VGPRs; raw s_barrier + lgkmcnt-only drain.
// R11 baseline: MFMA 16x16x16 per tile; D row=4q+reg, col=lane&15.

#define Bn 64
#define Rn 2048
#define Cn 32
#define On 32
#define In 16
#define RCH 16            // r per block
#define NRC2 (Rn / RCH)   // 128 r-chunks
#define NG 2              // fused b-groups of 32

typedef _Float16 half4v __attribute__((ext_vector_type(4)));
typedef float floatx4 __attribute__((ext_vector_type(4)));

// s_part: [NRC2][64 b][1024 co] f32 (32 MB)
// PHASE 0: Wfp = W fp32 (reads + converts + persists fp16 to Wh).
// PHASE 1/2: Wh fp16 read path (R21 body unchanged).
template <int PHASE>
__global__ __launch_bounds__(512, 1)
void upass(const float* __restrict__ x, const float* __restrict__ Wfp,
           _Float16* __restrict__ Wh, const float* __restrict__ vroute,
           float* __restrict__ s_part) {
    const int tid  = threadIdx.x;
    const int w    = tid >> 6;      // wave 0..7 -> c = 4w..4w+3
    const int lane = tid & 63;
    const int q    = lane >> 4;     // quad
    const int bl   = lane & 15;     // A row / B col / D col

    // XCD swizzle: the 2 bg-blocks of one rc are L and L+8 -> same XCD.
    const int L  = blockIdx.x;                  // [0,256)
    const int bg = (L >> 3) & 1;
    const int rc = (L & 7) | ((L >> 4) << 3);   // [0,128)
    const int b0 = bg * 32;

    // xs[rr][bb 32][20] halfs (pad 16->20: 8B-aligned b64, conflict-free)
    __shared__ __attribute__((aligned(16))) _Float16 xs[RCH * 32 * 20];
    __shared__ __attribute__((aligned(16))) float sums[2][2][16][8];

    // ---- v slice -> registers (r-invariant). g=0: b0+bl, g=1: b0+16+bl ----
    floatx4 v00[4], v01[4], v10[4], v11[4];
    if constexpr (PHASE > 0) {
        const float* vb0 = vroute + (size_t)(b0 + bl) * 1024 + 4 * q;
        const float* vb1 = vroute + (size_t)(b0 + 16 + bl) * 1024 + 4 * q;
#pragma unroll
        for (int t = 0; t < 4; ++t) {
            const int co = (w * 4 + t) * 32;
            v00[t] = *(const floatx4*)(vb0 + co);
            v01[t] = *(const floatx4*)(vb0 + co + 16);
            v10[t] = *(const floatx4*)(vb1 + co);
            v11[t] = *(const floatx4*)(vb1 + co + 16);
        }
    }

    // ---- preload x chunk -> fp16 LDS: 16 r x 32 b x 16 i ----
#pragma unroll
    for (int k = 0; k < 4; ++k) {
        const int u  = tid + k * 512;           // [0,2048)
        const int rr = u >> 7, bb = (u >> 2) & 31, iq = u & 3;
        const float4 xv = *(const float4*)(x + (size_t)(b0 + bb) * (Rn * In) +
                                           (size_t)(rc * RCH + rr) * In + iq * 4);
        union { _Float16 h[4]; uint2 u2; } p;
        p.h[0] = (_Float16)xv.x; p.h[1] = (_Float16)xv.y;
        p.h[2] = (_Float16)xv.z; p.h[3] = (_Float16)xv.w;
        *(uint2*)(xs + (rr * 32 + bb) * 20 + iq * 4) = p.u2;
    }
    __syncthreads();

    floatx4 accS0[8], accS1[8];
#pragma unroll
    for (int m = 0; m < 8; ++m) {
        accS0[m] = (floatx4){0.f, 0.f, 0.f, 0.f};
        accS1[m] = (floatx4){0.f, 0.f, 0.f, 0.f};
    }

    // A base: W[r, co = w*128 + m*16 + bl, i = 4q..4q+3]; per-r stride 16384 halfs
    const size_t abase = ((size_t)(rc * RCH) * 1024 + w * 128 + bl) * 16 + 4 * q;

    half4v a[8];
    half4v bf0, bf1;
    if constexpr (PHASE > 0) {
        const _Float16* Wp = Wh + abase;
#pragma unroll
        for (int m = 0; m < 8; ++m) a[m] = *(const half4v*)(Wp + m * 256);
        bf0 = *(const half4v*)(xs + bl * 20 + 4 * q);
        bf1 = *(const half4v*)(xs + (16 + bl) * 20 + 4 * q);
    }

    for (int rr = 0; rr < RCH; ++rr) {
        if constexpr (PHASE == 0) {
            // fp32 W read (1KB coalesced segments), in-reg cvt, fp16 persist.
            const size_t rb = abase + (size_t)rr * 16384;
            const float* Wf = Wfp + rb;
            half4v af[8];
#pragma unroll
            for (int m = 0; m < 8; ++m) {
                const float4 t4 = *(const float4*)(Wf + m * 256);
                af[m] = (half4v){(_Float16)t4.x, (_Float16)t4.y,
                                 (_Float16)t4.z, (_Float16)t4.w};
            }
            if (bg == 0) {
                _Float16* whp = Wh + rb;
#pragma unroll
                for (int m = 0; m < 8; ++m) *(half4v*)(whp + m * 256) = af[m];
            }
            const half4v b0v = *(const half4v*)(xs + (rr * 32 + bl) * 20 + 4 * q);
            const half4v b1v = *(const half4v*)(xs + (rr * 32 + 16 + bl) * 20 + 4 * q);
#pragma unroll
            for (int m = 0; m < 8; ++m) {
                accS0[m] = __builtin_amdgcn_mfma_f32_16x16x16f16(af[m], b0v, accS0[m], 0, 0, 0);
                accS1[m] = __builtin_amdgcn_mfma_f32_16x16x16f16(af[m], b1v, accS1[m], 0, 0, 0);
            }
        } else {
            const int rn = (rr + 1 < RCH) ? rr + 1 : rr;     // clamped prefetch idx
            const _Float16* Wn = Wh + abase + (size_t)rn * 16384;

            floatx4 D0[8], D1[8];
#pragma unroll
            for (int m = 0; m < 8; ++m) {
                D0[m] = __builtin_amdgcn_mfma_f32_16x16x16f16(
                            a[m], bf0, (floatx4){0.f, 0.f, 0.f, 0.f}, 0, 0, 0);
                D1[m] = __builtin_amdgcn_mfma_f32_16x16x16f16(
                            a[m], bf1, (floatx4){0.f, 0.f, 0.f, 0.f}, 0, 0, 0);
            }

            // issue rr+1 fragment loads NOW; in flight across the barrier.
            const half4v bn0 = *(const half4v*)(xs + (rn * 32 + bl) * 20 + 4 * q);
            const half4v bn1 = *(const half4v*)(xs + (rn * 32 + 16 + bl) * 20 + 4 * q);
#pragma unroll
            for (int m = 0; m < 8; ++m) a[m] = *(const half4v*)(Wn + m * 256);
            bf0 = bn0; bf1 = bn1;

            // logits l[b,c] = sum_o u*v ; tile 2t: o=4q+reg, 2t+1: o=16+4q+reg
            float e0[4], e1[4], se0 = 0.f, se1 = 0.f;
#pragma unroll
            for (int t = 0; t < 4; ++t) {
                float lp0 = D0[2*t].x * v00[t].x + D0[2*t].y * v00[t].y +
                            D0[2*t].z * v00[t].z + D0[2*t].w * v00[t].w +
                            D0[2*t+1].x * v01[t].x + D0[2*t+1].y * v01[t].y +
                            D0[2*t+1].z * v01[t].z + D0[2*t+1].w * v01[t].w;
                float lp1 = D1[2*t].x * v10[t].x + D1[2*t].y * v10[t].y +
                            D1[2*t].z * v10[t].z + D1[2*t].w * v10[t].w +
                            D1[2*t+1].x * v11[t].x + D1[2*t+1].y * v11[t].y +
                            D1[2*t+1].z * v11[t].z + D1[2*t+1].w * v11[t].w;
                lp0 += __shfl_xor(lp0, 16, 64);   // sum over quads (o coverage)
                lp0 += __shfl_xor(lp0, 32, 64);
                lp1 += __shfl_xor(lp1, 16, 64);
                lp1 += __shfl_xor(lp1, 32, 64);
                e0[t] = __expf(lp0); se0 += e0[t]; // no max-subtract (|l| small)
                e1[t] = __expf(lp1); se1 += e1[t];
            }
            if (lane < 32) sums[rr & 1][q][bl][w] = (q == 0) ? se0 : se1;
            // lgkmcnt-only drain: LDS write visible, W loads stay in flight.
            asm volatile("s_waitcnt lgkmcnt(0)" ::: "memory");
            __builtin_amdgcn_s_barrier();
            asm volatile("" ::: "memory");
            const floatx4 sa0 = *(const floatx4*)(&sums[rr & 1][0][bl][0]);
            const floatx4 sa1 = *(const floatx4*)(&sums[rr & 1][0][bl][4]);
            const floatx4 sb0 = *(const floatx4*)(&sums[rr & 1][1][bl][0]);
            const floatx4 sb1 = *(const floatx4*)(&sums[rr & 1][1][bl][4]);
            const float tot0 = sa0.x + sa0.y + sa0.z + sa0.w +
                               sa1.x + sa1.y + sa1.z + sa1.w;
            const float tot1 = sb0.x + sb0.y + sb0.z + sb0.w +
                               sb1.x + sb1.y + sb1.z + sb1.w;
            const float winv0 = __builtin_amdgcn_rcpf(tot0);
            const float winv1 = __builtin_amdgcn_rcpf(tot1);
#pragma unroll
            for (int t = 0; t < 4; ++t) {
                const float wt0 = e0[t] * winv0;
                const float wt1 = e1[t] * winv1;
                accS0[2*t]   += wt0 * D0[2*t];
                accS0[2*t+1] += wt0 * D0[2*t+1];
                accS1[2*t]   += wt1 * D1[2*t];
                accS1[2*t+1] += wt1 * D1[2*t+1];
            }
        }
    }

    // store: co = w*128 + m*16 + 4q + reg; g=0 rows b0+bl, g=1 rows b0+16+bl
    const size_t sb = (((size_t)rc * 64 + b0 + bl)) * 1024 + w * 128 + 4 * q;
#pragma unroll
    for (int m = 0; m < 8; ++m) {
        *(floatx4*)(s_part + sb + m * 16) = accS0[m];
        *(floatx4*)(s_part + sb + (size_t)16 * 1024 + m * 16) = accS1[m];
    }
}

// Fused reduce(128 rc-partials) + squash. Grid: 64 b x 8 co-octs = 512 blocks.
// Each block: 256 thr = 8 k-groups x 32 float4 covering a 128-co slice
// (= 4 full capsules c, so the o-norm is block-local).
__global__ __launch_bounds__(256)
void reduce_squash(const float* __restrict__ sp, float scale,
                   float* __restrict__ vout, const float* __restrict__ vprev,
                   float* __restrict__ vsum) {
    const int b = blockIdx.x >> 3, oct = blockIdx.x & 7;
    const int t = threadIdx.x;
    const int kg = t >> 5, ci = t & 31;
    const size_t base = (size_t)b * 1024 + (size_t)oct * 128 + (size_t)ci * 4;

    floatx4 acc0 = (floatx4){0.f, 0.f, 0.f, 0.f};
    floatx4 acc1 = (floatx4){0.f, 0.f, 0.f, 0.f};
#pragma unroll
    for (int k = kg * 16; k < kg * 16 + 16; k += 2) {
        acc0 += *(const floatx4*)(sp + (size_t)k * 65536 + base);
        acc1 += *(const floatx4*)(sp + (size_t)(k + 1) * 65536 + base);
    }
    const floatx4 acc = acc0 + acc1;

    __shared__ __attribute__((aligned(16))) float red[8][128];
    *(floatx4*)(&red[kg][ci * 4]) = acc;
    __syncthreads();

    if (t < 128) {                     // element f = t : c = oct*4 + (t>>5), o = t&31
        float s = 0.f;
#pragma unroll
        for (int g = 0; g < 8; ++g) s += red[g][t];
        s *= scale;
        float n2 = s * s;              // norm over o: lane bits 0..4
        n2 += __shfl_xor(n2, 1, 64);
        n2 += __shfl_xor(n2, 2, 64);
        n2 += __shfl_xor(n2, 4, 64);
        n2 += __shfl_xor(n2, 8, 64);
        n2 += __shfl_xor(n2, 16, 64);
        const float norm = sqrtf(n2);
        const float f = (n2 / (1.f + n2)) / (norm + 1e-8f);
        const float vv = s * f;
        const size_t o = (size_t)b * 1024 + (size_t)oct * 128 + t;
        if (vout) vout[o] = vv;
        if (vsum) vsum[o] = vv + vprev[o];
    }
}

extern "C" void kernel_launch(void* const* d_in, const int* in_sizes, int n_in,
                              void* d_out, int out_size, void* d_ws, size_t ws_size,
                              hipStream_t stream) {
    const float* x = (const float*)d_in[0];   // [64,2048,16]
    const float* W = (const float*)d_in[1];   // [2048,32,32,16]
    float* out = (float*)d_out;               // [64,32,32]

    char* ws = (char*)d_ws;
    _Float16* Wh  = (_Float16*)ws;                              // 64 MB
    float* s_part = (float*)(ws + (size_t)67108864);            // 32 MB
    float* v1     = (float*)(ws + (size_t)67108864 + 33554432);             // 256 KB
    float* v12    = (float*)(ws + (size_t)67108864 + 33554432 + 262144);    // 256 KB

    const int ublocks = NG * NRC2;   // 256

    // iter 1: reads W fp32, persists Wh fp16; 1/32 applied as squash pre-scale
    upass<0><<<ublocks, 512, 0, stream>>>(x, W, Wh, nullptr, s_part);
    reduce_squash<<<512, 256, 0, stream>>>(s_part, 1.f / 32.f, v1, nullptr, nullptr);

    // iter 2: logits = u.v1 ; keep only v12 = v1 + v2
    upass<1><<<ublocks, 512, 0, stream>>>(x, nullptr, Wh, v1, s_part);
    reduce_squash<<<512, 256, 0, stream>>>(s_part, 1.f, nullptr, v1, v12);

    // iter 3: logits = u.(v1+v2) ; output v3
    upass<2><<<ublocks, 512, 0, stream>>>(x, nullptr, Wh, v12, s_part);
    reduce_squash<<<512, 256, 0, stream>>>(s_part, 1.f, out, nullptr, nullptr);
}